// Round 10
// baseline (4619.035 us; speedup 1.0000x reference)
//
#include <hip/hip_runtime.h>
#include <hip/hip_cooperative_groups.h>
#include <cstdint>

namespace cg = cooperative_groups;

#define B_    8
#define T_    16384
#define NA_   512
#define A_    512
#define NIT_  32
#define NCH_  256           // 64-sample chunks per row
#define EPSV  1e-8f

typedef unsigned long long u64;
typedef __attribute__((ext_vector_type(8))) short bf16x8;
typedef __attribute__((ext_vector_type(4))) float f32x4;

// ws float-offset layout (~10.6 MB total)
#define OFF_INV   0
#define OFF_SELA  512
#define OFF_SELT  768
#define OFF_SELV  1024
#define OFF_CM    1280        // u64[8*512*256] -> 2,097,152 floats
#define OFF_RMA   2098432     // u64[4096]
#define OFF_RMB   2106624     // u64[4096]
#define OFF_XRA   2114816     // f32[8*16384]
#define OFF_XRB   2245888     // f32[8*16384]
#define OFF_DPK   2376960     // u32[512*512]   d as (hi|lo<<16)
#define MAIN_NEED 2639104
// compact fallback layout
#define OFF_SXR   OFF_CM
#define OFF_SCAND (OFF_CM + 131072)
#define S_NEED    (OFF_SCAND + 16)

__device__ __forceinline__ unsigned int encf(float f) {
    unsigned int u = __float_as_uint(f);
    return (u & 0x80000000u) ? ~u : (u | 0x80000000u);
}
__device__ __forceinline__ float decf(unsigned int e) {
    unsigned int u = (e & 0x80000000u) ? (e & 0x7fffffffu) : ~e;
    return __uint_as_float(u);
}
__device__ __forceinline__ u64 umax64(u64 a, u64 b) { return a > b ? a : b; }
__device__ __forceinline__ u64 enc64(float v, unsigned int flat) {
    return (((u64)encf(v)) << 32) | (unsigned int)~flat;
}
__device__ __forceinline__ u64 shfl_xor_u64(u64 v, int mask) {
    unsigned int lo = (unsigned int)v, hi = (unsigned int)(v >> 32);
    lo = __shfl_xor(lo, mask, 64);
    hi = __shfl_xor(hi, mask, 64);
    return (((u64)hi) << 32) | lo;
}
__device__ __forceinline__ u64 shfl_down_u64(u64 v, int off) {
    unsigned int lo = (unsigned int)v, hi = (unsigned int)(v >> 32);
    lo = __shfl_down(lo, off, 64);
    hi = __shfl_down(hi, off, 64);
    return (((u64)hi) << 32) | lo;
}
// bf16 round-to-nearest-even from fp32
__device__ __forceinline__ unsigned short f2bf(float v) {
    unsigned int u = __float_as_uint(v);
    return (unsigned short)((u + 0x7fffu + ((u >> 16) & 1u)) >> 16);
}

// ---------------- inv[a] = 1/(||d_a||+eps) ----------------
__global__ __launch_bounds__(64) void k_inv(const float* __restrict__ d, float* __restrict__ inv) {
    const int a = blockIdx.x, lane = threadIdx.x;
    const float* row = d + a * A_;
    float s = 0.f;
    for (int i = lane; i < A_; i += 64) { float v = row[i]; s = fmaf(v, v, s); }
    #pragma unroll
    for (int o = 32; o > 0; o >>= 1) s += __shfl_down(s, o, 64);
    if (lane == 0) inv[a] = 1.0f / (sqrtf(s) + EPSV);
}

// ---------------- d -> packed (hi | lo<<16) ----------------
__global__ __launch_bounds__(256) void k_split_d(const float* __restrict__ d,
                                                 unsigned int* __restrict__ dpk) {
    int id = blockIdx.x * 256 + threadIdx.x;           // 262144
    float v = d[id];
    unsigned short hb = f2bf(v);
    unsigned short lb = f2bf(v - __uint_as_float((unsigned int)hb << 16));
    dpk[id] = (unsigned int)hb | ((unsigned int)lb << 16);
}

// ---------------- initial full conv: 128 atoms x 256 t per block, LDS B-sharing ----------------
__global__ __launch_bounds__(512) void k_conv(const float* __restrict__ x,
                                              const unsigned int* __restrict__ dpk,
                                              const float* __restrict__ inv,
                                              u64* __restrict__ cm) {
    __shared__ float xf[776];
    __shared__ uint4 s_hh[4][197];      // 4 shift-copies, (hi,hi) pairs; aligned b128 reads
    __shared__ uint4 s_ll[4][197];
    const int tid = threadIdx.x;
    const int wave = tid >> 6, lane = tid & 63;
    const int cl = lane & 15, q = lane >> 4;
    const int wb = blockIdx.x * 256;
    const int gb = blockIdx.z;

    for (int i = tid; i < 776; i += 512) {
        int t = wb + i;
        xf[i] = (t < T_) ? x[gb * T_ + t] : 0.f;
    }
    __syncthreads();
    unsigned int* hw = (unsigned int*)s_hh;
    unsigned int* lw = (unsigned int*)s_ll;
    for (int i = tid; i < 772; i += 512) {
        #pragma unroll
        for (int s = 0; s < 4; ++s) {
            float xv = xf[i + s];
            unsigned short hb = f2bf(xv);
            unsigned short lb = f2bf(xv - __uint_as_float((unsigned int)hb << 16));
            hw[s * 788 + i] = (unsigned int)hb * 0x10001u;
            lw[s * 788 + i] = (unsigned int)lb * 0x10001u;
        }
    }
    __syncthreads();

    const int a_base = blockIdx.y * 128 + (wave & 1) * 64;
    const int t0l = (wave >> 1) * 64;
    const unsigned int* Ap[4];
    #pragma unroll
    for (int at = 0; at < 4; ++at)
        Ap[at] = dpk + ((a_base + 16 * at + cl) << 9) + 4 * q;
    const uint4* bhp = &s_hh[cl & 3][(t0l >> 2) + (cl >> 2) + q];
    const uint4* blp = &s_ll[cl & 3][(t0l >> 2) + (cl >> 2) + q];

    f32x4 acc[4][4];
    const f32x4 zero = {0.f, 0.f, 0.f, 0.f};
    #pragma unroll
    for (int at = 0; at < 4; ++at)
        #pragma unroll
        for (int tt = 0; tt < 4; ++tt) acc[at][tt] = zero;

    for (int j0 = 0; j0 < A_; j0 += 16) {
        union { uint4 u; bf16x8 f; } Af[4], bh[4], bl[4];
        #pragma unroll
        for (int at = 0; at < 4; ++at) Af[at].u = *(const uint4*)(Ap[at] + j0);
        #pragma unroll
        for (int tt = 0; tt < 4; ++tt) {
            bh[tt].u = bhp[4 * tt + (j0 >> 2)];
            bl[tt].u = blp[4 * tt + (j0 >> 2)];
        }
        #pragma unroll
        for (int tt = 0; tt < 4; ++tt)
            #pragma unroll
            for (int at = 0; at < 4; ++at)
                acc[at][tt] = __builtin_amdgcn_mfma_f32_16x16x32_bf16(Af[at].f, bh[tt].f, acc[at][tt], 0, 0, 0);
        #pragma unroll
        for (int tt = 0; tt < 4; ++tt)
            #pragma unroll
            for (int at = 0; at < 4; ++at)
                acc[at][tt] = __builtin_amdgcn_mfma_f32_16x16x32_bf16(Af[at].f, bl[tt].f, acc[at][tt], 0, 0, 0);
    }

    const int t0 = wb + t0l;
    const int ch = t0 >> 6;
    #pragma unroll
    for (int at = 0; at < 4; ++at) {
        #pragma unroll
        for (int r = 0; r < 4; ++r) {
            const int atom = a_base + 16 * at + 4 * q + r;
            const float iv = inv[atom];
            u64 m = 0ull;
            #pragma unroll
            for (int tt = 0; tt < 4; ++tt) {
                int t = t0 + 16 * tt + cl;
                m = umax64(m, enc64(acc[at][tt][r] * iv, (unsigned int)(atom * T_ + t)));
            }
            m = umax64(m, shfl_xor_u64(m, 1));
            m = umax64(m, shfl_xor_u64(m, 2));
            m = umax64(m, shfl_xor_u64(m, 4));
            m = umax64(m, shfl_xor_u64(m, 8));
            if (cl == 0)
                cm[((size_t)(gb * NA_ + atom) << 8) + ch] = m;
        }
    }
}

// ---------------- rm from cm (4 rows per block, wave per row) ----------------
__global__ __launch_bounds__(256) void k_tables(const u64* __restrict__ cm, u64* __restrict__ rm) {
    const int row = blockIdx.x * 4 + (threadIdx.x >> 6);
    const int lane = threadIdx.x & 63;
    const u64* p = cm + ((size_t)row << 8);
    u64 m = 0ull;
    #pragma unroll
    for (int k = 0; k < 4; ++k) m = umax64(m, p[lane + 64 * k]);
    #pragma unroll
    for (int o = 32; o > 0; o >>= 1) m = umax64(m, shfl_down_u64(m, o));
    if (lane == 0) rm[row] = m;
}

// ---------------- shared state + phases A-D as a device function ----------------
struct ShIt {
    u64 red4[4];
    float xf[1604];
    uint4 s_hh[4][405];
    uint4 s_ll[4][405];
};

// grid (32 atom-groups of 16, 8 batches), 256 threads (4 waves).
// A: argmax from rmPrev; B: xr ping-pong slice copy w/ patch; C: LDS staging;
// D: MFMA window conv for this block's 16 atoms, rewrite cm chunks.
__device__ void iter_AD(ShIt* sh,
                        const float* __restrict__ xrPrev, float* __restrict__ xrNext,
                        const float* __restrict__ d, const float* __restrict__ inv,
                        const unsigned int* __restrict__ dpk, u64* __restrict__ cm,
                        const u64* __restrict__ rmPrev,
                        int* __restrict__ selA, int* __restrict__ selT,
                        float* __restrict__ selV, int it) {
    const int ag = blockIdx.x, b = blockIdx.y, tid = threadIdx.x;
    const int wave = tid >> 6, lane = tid & 63;
    const int cl = lane & 15, q = lane >> 4;
    const int a0 = ag * 16;

    // ---- phase A: argmax (shfl-reduce, 1 barrier) ----
    const u64* rp = rmPrev + b * NA_;
    u64 m = umax64(rp[tid], rp[tid + 256]);
    #pragma unroll
    for (int o = 32; o > 0; o >>= 1) m = umax64(m, shfl_xor_u64(m, o));
    if (lane == 0) sh->red4[wave] = m;
    __syncthreads();
    const u64 win = umax64(umax64(sh->red4[0], sh->red4[1]),
                           umax64(sh->red4[2], sh->red4[3]));
    const unsigned int enc = (unsigned int)(win >> 32);
    const unsigned int flat = ~(unsigned int)win;
    const int asel = (int)(flat >> 14);
    const int tsel = (int)(flat & (T_ - 1));
    const float v = decf(enc);
    if (ag == 0 && tid == 0) {
        selA[it * B_ + b] = asel;
        selT[it * B_ + b] = tsel;
        selV[it * B_ + b] = v;
    }
    const int L = min(A_, (T_ - 1) - tsel);   // reference truncation quirk
    const float vv = v * inv[asel];

    // ---- phase B: xr ping-pong slice [ag*512, +512) ----
    #pragma unroll
    for (int k = 0; k < 2; ++k) {
        int t = ag * 512 + k * 256 + tid;
        float xv = xrPrev[b * T_ + t];
        int o = t - tsel;
        if (L > 0 && o >= 0 && o < L) xv = fmaf(-vv, d[asel * A_ + o], xv);
        xrNext[b * T_ + t] = xv;
    }

    if (L > 0) {
        const int tbeg = max(0, tsel - (A_ - 1));
        const int tend = tsel + L;               // <= 16383
        const int ab = tbeg & ~63;
        const int ae = (tend + 63) & ~63;        // <= T_
        const int W = ae - ab;                   // <= 1088
        const int nch = W >> 6;                  // <= 17
        const int NS = W + 512;

        // ---- phase C: patched fp32 window, then 4 shift-copies of bf16 pairs ----
        __syncthreads();
        for (int i = tid; i < NS + 3; i += 256) {
            int t = ab + i;
            float xv = (t < T_) ? xrPrev[b * T_ + t] : 0.f;
            int o = t - tsel;
            if (o >= 0 && o < L) xv = fmaf(-vv, d[asel * A_ + o], xv);
            sh->xf[i] = xv;
        }
        __syncthreads();
        unsigned int* hw = (unsigned int*)sh->s_hh;
        unsigned int* lw = (unsigned int*)sh->s_ll;
        for (int i = tid; i < NS; i += 256) {
            #pragma unroll
            for (int s = 0; s < 4; ++s) {
                float xv = sh->xf[i + s];
                unsigned short hb = f2bf(xv);
                unsigned short lb = f2bf(xv - __uint_as_float((unsigned int)hb << 16));
                hw[s * 1620 + i] = (unsigned int)hb * 0x10001u;
                lw[s * 1620 + i] = (unsigned int)lb * 0x10001u;
            }
        }
        __syncthreads();

        // ---- phase D: chunks c = wave, wave+4, ... (<=5 per wave) ----
        const unsigned int* Ap = dpk + ((a0 + cl) << 9) + 4 * q;
        float ivv[4];
        #pragma unroll
        for (int r = 0; r < 4; ++r) ivv[r] = inv[a0 + 4 * q + r];
        const uint4* bhp = &sh->s_hh[cl & 3][(cl >> 2) + q];
        const uint4* blp = &sh->s_ll[cl & 3][(cl >> 2) + q];

        for (int c = wave; c < nch; c += 4) {
            f32x4 acc[4];
            const f32x4 zero = {0.f, 0.f, 0.f, 0.f};
            #pragma unroll
            for (int tt = 0; tt < 4; ++tt) acc[tt] = zero;
            for (int j0 = 0; j0 < A_; j0 += 16) {
                union { uint4 u; bf16x8 f; } Af, bh[4], bl[4];
                Af.u = *(const uint4*)(Ap + j0);
                #pragma unroll
                for (int tt = 0; tt < 4; ++tt) {
                    int i4 = 16 * c + 4 * tt + (j0 >> 2);
                    bh[tt].u = bhp[i4];
                    bl[tt].u = blp[i4];
                }
                #pragma unroll
                for (int tt = 0; tt < 4; ++tt)
                    acc[tt] = __builtin_amdgcn_mfma_f32_16x16x32_bf16(Af.f, bh[tt].f, acc[tt], 0, 0, 0);
                #pragma unroll
                for (int tt = 0; tt < 4; ++tt)
                    acc[tt] = __builtin_amdgcn_mfma_f32_16x16x32_bf16(Af.f, bl[tt].f, acc[tt], 0, 0, 0);
            }
            #pragma unroll
            for (int r = 0; r < 4; ++r) {
                const int atom = a0 + 4 * q + r;
                u64 mm = 0ull;
                #pragma unroll
                for (int tt = 0; tt < 4; ++tt) {
                    int t = ab + 64 * c + 16 * tt + cl;
                    mm = umax64(mm, enc64(acc[tt][r] * ivv[r], (unsigned int)(atom * T_ + t)));
                }
                mm = umax64(mm, shfl_xor_u64(mm, 1));
                mm = umax64(mm, shfl_xor_u64(mm, 2));
                mm = umax64(mm, shfl_xor_u64(mm, 4));
                mm = umax64(mm, shfl_xor_u64(mm, 8));
                if (cl == 0)
                    cm[((size_t)(b * NA_ + atom) << 8) + (ab >> 6) + c] = mm;
            }
        }
    }
}

// ---------------- persistent cooperative kernel: all 32 iterations ----------------
__global__ __launch_bounds__(256) void k_iters(float* xrA, float* xrB,
                                               const float* __restrict__ d,
                                               const float* __restrict__ inv,
                                               const unsigned int* __restrict__ dpk,
                                               u64* __restrict__ cm,
                                               u64* rmA, u64* rmB,
                                               int* __restrict__ selA,
                                               int* __restrict__ selT,
                                               float* __restrict__ selV) {
    cg::grid_group grid = cg::this_grid();
    __shared__ ShIt sh;
    const int ag = blockIdx.x, b = blockIdx.y, tid = threadIdx.x;
    const int wave = tid >> 6, lane = tid & 63;
    const int a0 = ag * 16;

    for (int it = 0; it < NIT_; ++it) {
        const float* xp = (it & 1) ? xrB : xrA;
        float*       xn = (it & 1) ? xrA : xrB;
        const u64*   ro = (it & 1) ? rmB : rmA;
        u64*         rn = (it & 1) ? rmA : rmB;
        iter_AD(&sh, xp, xn, d, inv, dpk, cm, ro, selA, selT, selV, it);
        __threadfence();
        grid.sync();                     // cm/xr writes visible grid-wide
        // ---- phase E: rm for this block's 16 rows, wave per 4 rows ----
        #pragma unroll
        for (int rr = 0; rr < 4; ++rr) {
            const int row = a0 + wave * 4 + rr;
            const u64* p = cm + ((size_t)(b * NA_ + row) << 8);
            u64 m = umax64(umax64(p[lane], p[lane + 64]),
                           umax64(p[lane + 128], p[lane + 192]));
            #pragma unroll
            for (int o = 32; o > 0; o >>= 1) m = umax64(m, shfl_down_u64(m, o));
            if (lane == 0) rn[b * NA_ + row] = m;
        }
        __threadfence();
        grid.sync();                     // rm visible before next selection
    }
}

// ---------------- non-cooperative fallback: phases A-D as one kernel per iter ----------------
__global__ __launch_bounds__(256) void k_itAD(const float* __restrict__ xrPrev,
                                              float* __restrict__ xrNext,
                                              const float* __restrict__ d,
                                              const float* __restrict__ inv,
                                              const unsigned int* __restrict__ dpk,
                                              u64* __restrict__ cm,
                                              const u64* __restrict__ rmPrev,
                                              int* __restrict__ selA,
                                              int* __restrict__ selT,
                                              float* __restrict__ selV,
                                              int it) {
    __shared__ ShIt sh;
    iter_AD(&sh, xrPrev, xrNext, d, inv, dpk, cm, rmPrev, selA, selT, selV, it);
}

// ---------------- slow fallback (tiny ws): residual-space recompute ----------------
__global__ void s_init(const float* __restrict__ x, float* __restrict__ xr,
                       u64* __restrict__ cand) {
    int i = blockIdx.x * 256 + threadIdx.x;
    if (i < B_ * T_) xr[i] = x[i];
    if (i < B_) cand[i] = 0ull;
}
__global__ __launch_bounds__(256) void s_scan(const float* __restrict__ xr,
                                              const float* __restrict__ d,
                                              const float* __restrict__ inv,
                                              u64* __restrict__ cand) {
    __shared__ float dLs[A_];
    __shared__ u64 redU[256];
    const int aB = blockIdx.x, b = blockIdx.y, tid = threadIdx.x;
    const float iv = inv[aB];
    for (int i = tid; i < A_; i += 256) dLs[i] = d[aB * A_ + i] * iv;
    __syncthreads();
    const float* xb = xr + b * T_;
    u64 best = 0ull;
    for (int t = tid; t < T_; t += 256) {
        float acc = 0.f;
        int lim = min(A_, T_ - t);
        for (int i = 0; i < lim; ++i) acc = fmaf(dLs[i], xb[t + i], acc);
        best = umax64(best, enc64(acc, (unsigned int)(aB * T_ + t)));
    }
    redU[tid] = best;
    __syncthreads();
    for (int s = 128; s > 0; s >>= 1) {
        if (tid < s) redU[tid] = umax64(redU[tid], redU[tid + s]);
        __syncthreads();
    }
    if (tid == 0) atomicMax(&cand[b], redU[0]);
}
__global__ void s_apply(float* __restrict__ xr, const float* __restrict__ d,
                        const float* __restrict__ inv, u64* __restrict__ cand,
                        int* selA, int* selT, float* selV, int it) {
    const int b = blockIdx.x, tid = threadIdx.x;
    u64 win = cand[b];
    unsigned int enc = (unsigned int)(win >> 32);
    unsigned int flat = ~(unsigned int)win;
    int a = (int)(flat >> 14), t = (int)(flat & (T_ - 1));
    float v = decf(enc);
    if (tid == 0) { selA[it * B_ + b] = a; selT[it * B_ + b] = t; selV[it * B_ + b] = v; }
    float vvl = v * inv[a];
    int L = min(A_, (T_ - 1) - t);
    for (int o = tid; o < L; o += 256) xr[b * T_ + t + o] -= vvl * d[a * A_ + o];
    if (tid == 0) cand[b] = 0ull;
}

// ---------------- reconstruct (residual, recon) from selections ----------------
__global__ __launch_bounds__(256) void k_final(const float* __restrict__ x,
                                               const float* __restrict__ d,
                                               const int* __restrict__ selA,
                                               const int* __restrict__ selT,
                                               const float* __restrict__ selV,
                                               const float* __restrict__ inv,
                                               float* __restrict__ out) {
    const int gid = blockIdx.x * 256 + threadIdx.x;
    const int b = gid >> 14;
    const int t = gid & (T_ - 1);
    float r = x[gid];
    float rec = 0.f;
    for (int k = 0; k < NIT_; ++k) {           // sequential: reference fp order
        int a  = selA[k * B_ + b];
        int ts = selT[k * B_ + b];
        float vvl = selV[k * B_ + b] * inv[a];
        int o = t - ts;
        int L = min(A_, (T_ - 1) - ts);
        if (o >= 0 && o < L) {
            float c = vvl * d[a * A_ + o];
            r -= c;
            rec += c;
        }
    }
    out[gid] = r;
    out[B_ * T_ + gid] = rec;
}

extern "C" void kernel_launch(void* const* d_in, const int* in_sizes, int n_in,
                              void* d_out, int out_size, void* d_ws, size_t ws_size,
                              hipStream_t stream) {
    const float* x = (const float*)d_in[0];
    const float* d = (const float*)d_in[1];
    float* out = (float*)d_out;
    float* ws = (float*)d_ws;
    const size_t wsf = ws_size / sizeof(float);

    float* inv  = ws + OFF_INV;
    int*   selA = (int*)(ws + OFF_SELA);
    int*   selT = (int*)(ws + OFF_SELT);
    float* selV = ws + OFF_SELV;

    if (wsf < (size_t)S_NEED) return;   // hopeless

    k_inv<<<dim3(NA_), dim3(64), 0, stream>>>(d, inv);

    if (wsf >= (size_t)MAIN_NEED) {
        u64* cm  = (u64*)(ws + OFF_CM);
        u64* rmA = (u64*)(ws + OFF_RMA);
        u64* rmB = (u64*)(ws + OFF_RMB);
        float* xrA = ws + OFF_XRA;
        float* xrB = ws + OFF_XRB;
        unsigned int* dpk = (unsigned int*)(ws + OFF_DPK);

        k_split_d<<<dim3(NA_ * A_ / 256), dim3(256), 0, stream>>>(d, dpk);
        hipMemcpyAsync(xrA, x, (size_t)B_ * T_ * sizeof(float),
                       hipMemcpyDeviceToDevice, stream);
        k_conv<<<dim3(T_ / 256, NA_ / 128, B_), dim3(512), 0, stream>>>(x, dpk, inv, cm);
        k_tables<<<dim3(B_ * NA_ / 4), dim3(256), 0, stream>>>(cm, rmA);

        const float* dc = d;
        const float* ic = inv;
        const unsigned int* dc2 = dpk;
        void* kargs[] = {(void*)&xrA, (void*)&xrB, (void*)&dc, (void*)&ic,
                         (void*)&dc2, (void*)&cm, (void*)&rmA, (void*)&rmB,
                         (void*)&selA, (void*)&selT, (void*)&selV};
        hipError_t ce = hipLaunchCooperativeKernel((const void*)k_iters,
                                                   dim3(NA_ / 16, B_), dim3(256),
                                                   kargs, 0, stream);
        if (ce != hipSuccess) {
            // per-iteration fallback: same device code, separate launches
            for (int it = 0; it < NIT_; ++it) {
                const float* xp = (it & 1) ? xrB : xrA;
                float*       xn = (it & 1) ? xrA : xrB;
                const u64*   ro = (it & 1) ? rmB : rmA;
                u64*         rn = (it & 1) ? rmA : rmB;
                k_itAD<<<dim3(NA_ / 16, B_), dim3(256), 0, stream>>>(xp, xn, d, inv, dpk,
                                                                     cm, ro, selA, selT, selV, it);
                k_tables<<<dim3(B_ * NA_ / 4), dim3(256), 0, stream>>>(cm, rn);
            }
        }
    } else {
        float* xr = ws + OFF_SXR;
        u64* cand = (u64*)(ws + OFF_SCAND);
        s_init<<<dim3((B_ * T_ + 255) / 256), dim3(256), 0, stream>>>(x, xr, cand);
        for (int it = 0; it < NIT_; ++it) {
            s_scan<<<dim3(NA_, B_), dim3(256), 0, stream>>>(xr, d, inv, cand);
            s_apply<<<dim3(B_), dim3(256), 0, stream>>>(xr, d, inv, cand, selA, selT, selV, it);
        }
    }

    k_final<<<dim3(B_ * T_ / 256), dim3(256), 0, stream>>>(x, d, selA, selT, selV, inv, out);
}

// Round 12
// 1321.563 us; speedup vs baseline: 3.4951x; 3.4951x over previous
//
#include <hip/hip_runtime.h>
#include <cstdint>

#define B_    8
#define T_    16384
#define NA_   512
#define A_    512
#define NIT_  32
#define NCH_  256           // 64-sample chunks per row
#define EPSV  1e-8f

typedef unsigned long long u64;
typedef __attribute__((ext_vector_type(8))) short bf16x8;
typedef __attribute__((ext_vector_type(4))) float f32x4;

// ws float-offset layout (~10.6 MB total)
#define OFF_INV   0
#define OFF_SELA  512
#define OFF_SELT  768
#define OFF_SELV  1024
#define OFF_CM    1280        // u64[8*512*256] -> 2,097,152 floats
#define OFF_RMA   2098432     // u64[4096]
#define OFF_RMB   2106624     // u64[4096]
#define OFF_XRA   2114816     // f32[8*16384]
#define OFF_XRB   2245888     // f32[8*16384]
#define OFF_DPK   2376960     // u32[512*512]   d as (hi|lo<<16)
#define MAIN_NEED 2639104
// compact fallback layout
#define OFF_SXR   OFF_CM
#define OFF_SCAND (OFF_CM + 131072)
#define S_NEED    (OFF_SCAND + 16)

__device__ __forceinline__ unsigned int encf(float f) {
    unsigned int u = __float_as_uint(f);
    return (u & 0x80000000u) ? ~u : (u | 0x80000000u);
}
__device__ __forceinline__ float decf(unsigned int e) {
    unsigned int u = (e & 0x80000000u) ? (e & 0x7fffffffu) : ~e;
    return __uint_as_float(u);
}
__device__ __forceinline__ u64 umax64(u64 a, u64 b) { return a > b ? a : b; }
__device__ __forceinline__ u64 enc64(float v, unsigned int flat) {
    return (((u64)encf(v)) << 32) | (unsigned int)~flat;
}
__device__ __forceinline__ u64 shfl_xor_u64(u64 v, int mask) {
    unsigned int lo = (unsigned int)v, hi = (unsigned int)(v >> 32);
    lo = __shfl_xor(lo, mask, 64);
    hi = __shfl_xor(hi, mask, 64);
    return (((u64)hi) << 32) | lo;
}
__device__ __forceinline__ u64 shfl_down_u64(u64 v, int off) {
    unsigned int lo = (unsigned int)v, hi = (unsigned int)(v >> 32);
    lo = __shfl_down(lo, off, 64);
    hi = __shfl_down(hi, off, 64);
    return (((u64)hi) << 32) | lo;
}
// bf16 round-to-nearest-even from fp32
__device__ __forceinline__ unsigned short f2bf(float v) {
    unsigned int u = __float_as_uint(v);
    return (unsigned short)((u + 0x7fffu + ((u >> 16) & 1u)) >> 16);
}

// ---------------- inv[a] = 1/(||d_a||+eps) ----------------
__global__ __launch_bounds__(64) void k_inv(const float* __restrict__ d, float* __restrict__ inv) {
    const int a = blockIdx.x, lane = threadIdx.x;
    const float* row = d + a * A_;
    float s = 0.f;
    for (int i = lane; i < A_; i += 64) { float v = row[i]; s = fmaf(v, v, s); }
    #pragma unroll
    for (int o = 32; o > 0; o >>= 1) s += __shfl_down(s, o, 64);
    if (lane == 0) inv[a] = 1.0f / (sqrtf(s) + EPSV);
}

// ---------------- d -> packed (hi | lo<<16) ----------------
__global__ __launch_bounds__(256) void k_split_d(const float* __restrict__ d,
                                                 unsigned int* __restrict__ dpk) {
    int id = blockIdx.x * 256 + threadIdx.x;           // 262144
    float v = d[id];
    unsigned short hb = f2bf(v);
    unsigned short lb = f2bf(v - __uint_as_float((unsigned int)hb << 16));
    dpk[id] = (unsigned int)hb | ((unsigned int)lb << 16);
}

// ---------------- initial full conv: 128 atoms x 256 t per block, LDS B-sharing ----------------
// LDS copy stride 202 uint4 = 808 dwords == 8 (mod 32): conflict-free b128 reads.
// blocks with blockIdx.y==0 also persist x into xrA (replaces the memcpy node).
__global__ __launch_bounds__(512) void k_conv(const float* __restrict__ x,
                                              const unsigned int* __restrict__ dpk,
                                              const float* __restrict__ inv,
                                              u64* __restrict__ cm,
                                              float* __restrict__ xrA) {
    __shared__ float xf[776];
    __shared__ uint4 s_hh[4][202];
    __shared__ uint4 s_ll[4][202];
    const int tid = threadIdx.x;
    const int wave = tid >> 6, lane = tid & 63;
    const int cl = lane & 15, q = lane >> 4;
    const int wb = blockIdx.x * 256;
    const int gb = blockIdx.z;

    for (int i = tid; i < 776; i += 512) {
        int t = wb + i;
        float xv = (t < T_) ? x[gb * T_ + t] : 0.f;
        xf[i] = xv;
        if (blockIdx.y == 0 && i < 256) xrA[gb * T_ + wb + i] = xv;
    }
    __syncthreads();
    unsigned int* hw = (unsigned int*)s_hh;
    unsigned int* lw = (unsigned int*)s_ll;
    for (int i = tid; i < 772; i += 512) {
        #pragma unroll
        for (int s = 0; s < 4; ++s) {
            float xv = xf[i + s];
            unsigned short hb = f2bf(xv);
            unsigned short lb = f2bf(xv - __uint_as_float((unsigned int)hb << 16));
            hw[s * 808 + i] = (unsigned int)hb * 0x10001u;
            lw[s * 808 + i] = (unsigned int)lb * 0x10001u;
        }
    }
    __syncthreads();

    const int a_base = blockIdx.y * 128 + (wave & 1) * 64;
    const int t0l = (wave >> 1) * 64;
    const unsigned int* Ap[4];
    #pragma unroll
    for (int at = 0; at < 4; ++at)
        Ap[at] = dpk + ((a_base + 16 * at + cl) << 9) + 4 * q;
    const uint4* bhp = &s_hh[cl & 3][(t0l >> 2) + (cl >> 2) + q];
    const uint4* blp = &s_ll[cl & 3][(t0l >> 2) + (cl >> 2) + q];

    f32x4 acc[4][4];
    const f32x4 zero = {0.f, 0.f, 0.f, 0.f};
    #pragma unroll
    for (int at = 0; at < 4; ++at)
        #pragma unroll
        for (int tt = 0; tt < 4; ++tt) acc[at][tt] = zero;

    for (int j0 = 0; j0 < A_; j0 += 16) {
        union { uint4 u; bf16x8 f; } Af[4], bh[4], bl[4];
        #pragma unroll
        for (int at = 0; at < 4; ++at) Af[at].u = *(const uint4*)(Ap[at] + j0);
        #pragma unroll
        for (int tt = 0; tt < 4; ++tt) {
            bh[tt].u = bhp[4 * tt + (j0 >> 2)];
            bl[tt].u = blp[4 * tt + (j0 >> 2)];
        }
        #pragma unroll
        for (int tt = 0; tt < 4; ++tt)
            #pragma unroll
            for (int at = 0; at < 4; ++at)
                acc[at][tt] = __builtin_amdgcn_mfma_f32_16x16x32_bf16(Af[at].f, bh[tt].f, acc[at][tt], 0, 0, 0);
        #pragma unroll
        for (int tt = 0; tt < 4; ++tt)
            #pragma unroll
            for (int at = 0; at < 4; ++at)
                acc[at][tt] = __builtin_amdgcn_mfma_f32_16x16x32_bf16(Af[at].f, bl[tt].f, acc[at][tt], 0, 0, 0);
    }

    const int t0 = wb + t0l;
    const int ch = t0 >> 6;
    #pragma unroll
    for (int at = 0; at < 4; ++at) {
        #pragma unroll
        for (int r = 0; r < 4; ++r) {
            const int atom = a_base + 16 * at + 4 * q + r;
            const float iv = inv[atom];
            u64 m = 0ull;
            #pragma unroll
            for (int tt = 0; tt < 4; ++tt) {
                int t = t0 + 16 * tt + cl;
                m = umax64(m, enc64(acc[at][tt][r] * iv, (unsigned int)(atom * T_ + t)));
            }
            m = umax64(m, shfl_xor_u64(m, 1));
            m = umax64(m, shfl_xor_u64(m, 2));
            m = umax64(m, shfl_xor_u64(m, 4));
            m = umax64(m, shfl_xor_u64(m, 8));
            if (cl == 0)
                cm[((size_t)(gb * NA_ + atom) << 8) + ch] = m;
        }
    }
}

// ---------------- rm from cm (4 rows per block, wave per row) ----------------
__global__ __launch_bounds__(256) void k_tables(const u64* __restrict__ cm, u64* __restrict__ rm) {
    const int row = blockIdx.x * 4 + (threadIdx.x >> 6);
    const int lane = threadIdx.x & 63;
    const u64* p = cm + ((size_t)row << 8);
    u64 m = 0ull;
    #pragma unroll
    for (int k = 0; k < 4; ++k) m = umax64(m, p[lane + 64 * k]);
    #pragma unroll
    for (int o = 32; o > 0; o >>= 1) m = umax64(m, shfl_down_u64(m, o));
    if (lane == 0) rm[row] = m;
}

// ---------------- fully fused per-iteration kernel ----------------
// grid (32 atom-groups of 16, 8 batches), 256 threads (4 waves). Each block OWNS
// its 16 cm/rm rows (phase D writes them, phase E rescans them) -> no cross-block
// deps inside a launch; next iteration's argmax dependency rides the launch
// boundary. LDS copy stride 410 uint4 = 1640 dwords == 8 (mod 32): conflict-free.
__global__ __launch_bounds__(256) void k_it(const float* __restrict__ xrPrev,
                                            float* __restrict__ xrNext,
                                            const float* __restrict__ d,
                                            const float* __restrict__ inv,
                                            const unsigned int* __restrict__ dpk,
                                            u64* __restrict__ cm,
                                            const u64* __restrict__ rmPrev,
                                            u64* __restrict__ rmNext,
                                            int* __restrict__ selA,
                                            int* __restrict__ selT,
                                            float* __restrict__ selV,
                                            int it) {
    __shared__ u64 red4[4];
    __shared__ float xf[1604];
    __shared__ uint4 s_hh[4][410];
    __shared__ uint4 s_ll[4][410];
    const int ag = blockIdx.x, b = blockIdx.y, tid = threadIdx.x;
    const int wave = tid >> 6, lane = tid & 63;
    const int cl = lane & 15, q = lane >> 4;
    const int a0 = ag * 16;

    // ---- phase A: argmax from rmPrev (shfl-reduce, 1 barrier) ----
    const u64* rp = rmPrev + b * NA_;
    u64 am = umax64(rp[tid], rp[tid + 256]);
    #pragma unroll
    for (int o = 32; o > 0; o >>= 1) am = umax64(am, shfl_xor_u64(am, o));
    if (lane == 0) red4[wave] = am;
    __syncthreads();
    const u64 win = umax64(umax64(red4[0], red4[1]), umax64(red4[2], red4[3]));
    const unsigned int enc = (unsigned int)(win >> 32);
    const unsigned int flat = ~(unsigned int)win;
    // defensive clamps: garbage rm (poison / replay anomaly) must not fault
    const int asel = (int)((flat >> 14) & (NA_ - 1));
    const int tsel = (int)(flat & (T_ - 1));
    const float v = decf(enc);
    if (ag == 0 && tid == 0) {
        selA[it * B_ + b] = asel;
        selT[it * B_ + b] = tsel;
        selV[it * B_ + b] = v;
    }
    const int L = min(A_, (T_ - 1) - tsel);   // reference truncation quirk
    const float vv = v * inv[asel];

    // ---- phase B: xr ping-pong slice [ag*512, +512) ----
    #pragma unroll
    for (int k = 0; k < 2; ++k) {
        int t = ag * 512 + k * 256 + tid;
        float xv = xrPrev[b * T_ + t];
        int o = t - tsel;
        if (L > 0 && o >= 0 && o < L) xv = fmaf(-vv, d[asel * A_ + o], xv);
        xrNext[b * T_ + t] = xv;
    }

    if (L > 0) {
        const int tbeg = max(0, tsel - (A_ - 1));
        const int tend = tsel + L;               // <= 16383
        const int ab = tbeg & ~63;
        const int ae = (tend + 63) & ~63;        // <= T_
        const int W = ae - ab;                   // <= 1088 (window <=1023 + rounding)
        const int nch = W >> 6;                  // <= 17
        const int NS = W + 512;                  // <= 1600

        // ---- phase C: patched fp32 window, then 4 shift-copies of bf16 pairs ----
        __syncthreads();
        for (int i = tid; i < NS + 3; i += 256) {
            int t = ab + i;
            float xv = (t < T_) ? xrPrev[b * T_ + t] : 0.f;
            int o = t - tsel;
            if (o >= 0 && o < L) xv = fmaf(-vv, d[asel * A_ + o], xv);
            xf[i] = xv;
        }
        __syncthreads();
        unsigned int* hw = (unsigned int*)s_hh;
        unsigned int* lw = (unsigned int*)s_ll;
        for (int i = tid; i < NS; i += 256) {
            #pragma unroll
            for (int s = 0; s < 4; ++s) {
                float xv = xf[i + s];
                unsigned short hb = f2bf(xv);
                unsigned short lb = f2bf(xv - __uint_as_float((unsigned int)hb << 16));
                hw[s * 1640 + i] = (unsigned int)hb * 0x10001u;
                lw[s * 1640 + i] = (unsigned int)lb * 0x10001u;
            }
        }
        __syncthreads();

        // ---- phase D: chunks c = wave, wave+4, ... (<=5 per wave) ----
        const unsigned int* Ap = dpk + ((a0 + cl) << 9) + 4 * q;
        float ivv[4];
        #pragma unroll
        for (int r = 0; r < 4; ++r) ivv[r] = inv[a0 + 4 * q + r];
        const uint4* bhp = &s_hh[cl & 3][(cl >> 2) + q];
        const uint4* blp = &s_ll[cl & 3][(cl >> 2) + q];

        for (int c = wave; c < nch; c += 4) {
            f32x4 acc[4];
            const f32x4 zero = {0.f, 0.f, 0.f, 0.f};
            #pragma unroll
            for (int tt = 0; tt < 4; ++tt) acc[tt] = zero;
            for (int j0 = 0; j0 < A_; j0 += 16) {
                union { uint4 u; bf16x8 f; } Af, bh[4], bl[4];
                Af.u = *(const uint4*)(Ap + j0);
                #pragma unroll
                for (int tt = 0; tt < 4; ++tt) {
                    int i4 = 16 * c + 4 * tt + (j0 >> 2);
                    bh[tt].u = bhp[i4];
                    bl[tt].u = blp[i4];
                }
                #pragma unroll
                for (int tt = 0; tt < 4; ++tt)
                    acc[tt] = __builtin_amdgcn_mfma_f32_16x16x32_bf16(Af.f, bh[tt].f, acc[tt], 0, 0, 0);
                #pragma unroll
                for (int tt = 0; tt < 4; ++tt)
                    acc[tt] = __builtin_amdgcn_mfma_f32_16x16x32_bf16(Af.f, bl[tt].f, acc[tt], 0, 0, 0);
            }
            #pragma unroll
            for (int r = 0; r < 4; ++r) {
                const int atom = a0 + 4 * q + r;
                u64 mm = 0ull;
                #pragma unroll
                for (int tt = 0; tt < 4; ++tt) {
                    int t = ab + 64 * c + 16 * tt + cl;
                    mm = umax64(mm, enc64(acc[tt][r] * ivv[r], (unsigned int)(atom * T_ + t)));
                }
                mm = umax64(mm, shfl_xor_u64(mm, 1));
                mm = umax64(mm, shfl_xor_u64(mm, 2));
                mm = umax64(mm, shfl_xor_u64(mm, 4));
                mm = umax64(mm, shfl_xor_u64(mm, 8));
                if (cl == 0)
                    cm[((size_t)(b * NA_ + atom) << 8) + (ab >> 6) + c] = mm;
            }
        }
        __syncthreads();   // own-row cm writes visible block-wide
    }

    // ---- phase E: rm for this block's 16 rows, wave per 4 rows, lane-coalesced ----
    #pragma unroll
    for (int rr = 0; rr < 4; ++rr) {
        const int row = a0 + wave * 4 + rr;
        const u64* p = cm + ((size_t)(b * NA_ + row) << 8);
        u64 m = umax64(umax64(p[lane], p[lane + 64]),
                       umax64(p[lane + 128], p[lane + 192]));
        #pragma unroll
        for (int o = 32; o > 0; o >>= 1) m = umax64(m, shfl_down_u64(m, o));
        if (lane == 0) rmNext[b * NA_ + row] = m;
    }
}

// ---------------- slow fallback (tiny ws): residual-space recompute ----------------
__global__ void s_init(const float* __restrict__ x, float* __restrict__ xr,
                       u64* __restrict__ cand) {
    int i = blockIdx.x * 256 + threadIdx.x;
    if (i < B_ * T_) xr[i] = x[i];
    if (i < B_) cand[i] = 0ull;
}
__global__ __launch_bounds__(256) void s_scan(const float* __restrict__ xr,
                                              const float* __restrict__ d,
                                              const float* __restrict__ inv,
                                              u64* __restrict__ cand) {
    __shared__ float dLs[A_];
    __shared__ u64 redU[256];
    const int aB = blockIdx.x, b = blockIdx.y, tid = threadIdx.x;
    const float iv = inv[aB];
    for (int i = tid; i < A_; i += 256) dLs[i] = d[aB * A_ + i] * iv;
    __syncthreads();
    const float* xb = xr + b * T_;
    u64 best = 0ull;
    for (int t = tid; t < T_; t += 256) {
        float acc = 0.f;
        int lim = min(A_, T_ - t);
        for (int i = 0; i < lim; ++i) acc = fmaf(dLs[i], xb[t + i], acc);
        best = umax64(best, enc64(acc, (unsigned int)(aB * T_ + t)));
    }
    redU[tid] = best;
    __syncthreads();
    for (int s = 128; s > 0; s >>= 1) {
        if (tid < s) redU[tid] = umax64(redU[tid], redU[tid + s]);
        __syncthreads();
    }
    if (tid == 0) atomicMax(&cand[b], redU[0]);
}
__global__ void s_apply(float* __restrict__ xr, const float* __restrict__ d,
                        const float* __restrict__ inv, u64* __restrict__ cand,
                        int* selA, int* selT, float* selV, int it) {
    const int b = blockIdx.x, tid = threadIdx.x;
    u64 win = cand[b];
    unsigned int enc = (unsigned int)(win >> 32);
    unsigned int flat = ~(unsigned int)win;
    int a = (int)((flat >> 14) & (NA_ - 1)), t = (int)(flat & (T_ - 1));
    float v = decf(enc);
    if (tid == 0) { selA[it * B_ + b] = a; selT[it * B_ + b] = t; selV[it * B_ + b] = v; }
    float vvl = v * inv[a];
    int L = min(A_, (T_ - 1) - t);
    for (int o = tid; o < L; o += 256) xr[b * T_ + t + o] -= vvl * d[a * A_ + o];
    if (tid == 0) cand[b] = 0ull;
}

// ---------------- reconstruct (residual, recon) from selections ----------------
__global__ __launch_bounds__(256) void k_final(const float* __restrict__ x,
                                               const float* __restrict__ d,
                                               const int* __restrict__ selA,
                                               const int* __restrict__ selT,
                                               const float* __restrict__ selV,
                                               const float* __restrict__ inv,
                                               float* __restrict__ out) {
    const int gid = blockIdx.x * 256 + threadIdx.x;
    const int b = gid >> 14;
    const int t = gid & (T_ - 1);
    float r = x[gid];
    float rec = 0.f;
    for (int k = 0; k < NIT_; ++k) {           // sequential: reference fp order
        int a  = selA[k * B_ + b] & (NA_ - 1);
        int ts = selT[k * B_ + b] & (T_ - 1);
        float vvl = selV[k * B_ + b] * inv[a];
        int o = t - ts;
        int L = min(A_, (T_ - 1) - ts);
        if (o >= 0 && o < L) {
            float c = vvl * d[a * A_ + o];
            r -= c;
            rec += c;
        }
    }
    out[gid] = r;
    out[B_ * T_ + gid] = rec;
}

extern "C" void kernel_launch(void* const* d_in, const int* in_sizes, int n_in,
                              void* d_out, int out_size, void* d_ws, size_t ws_size,
                              hipStream_t stream) {
    const float* x = (const float*)d_in[0];
    const float* d = (const float*)d_in[1];
    float* out = (float*)d_out;
    float* ws = (float*)d_ws;
    const size_t wsf = ws_size / sizeof(float);

    float* inv  = ws + OFF_INV;
    int*   selA = (int*)(ws + OFF_SELA);
    int*   selT = (int*)(ws + OFF_SELT);
    float* selV = ws + OFF_SELV;

    if (wsf < (size_t)S_NEED) return;   // hopeless

    k_inv<<<dim3(NA_), dim3(64), 0, stream>>>(d, inv);

    if (wsf >= (size_t)MAIN_NEED) {
        u64* cm  = (u64*)(ws + OFF_CM);
        u64* rmA = (u64*)(ws + OFF_RMA);
        u64* rmB = (u64*)(ws + OFF_RMB);
        float* xrA = ws + OFF_XRA;
        float* xrB = ws + OFF_XRB;
        unsigned int* dpk = (unsigned int*)(ws + OFF_DPK);

        k_split_d<<<dim3(NA_ * A_ / 256), dim3(256), 0, stream>>>(d, dpk);
        k_conv<<<dim3(T_ / 256, NA_ / 128, B_), dim3(512), 0, stream>>>(x, dpk, inv, cm, xrA);
        k_tables<<<dim3(B_ * NA_ / 4), dim3(256), 0, stream>>>(cm, rmA);

        for (int it = 0; it < NIT_; ++it) {
            const float* xp = (it & 1) ? xrB : xrA;
            float*       xn = (it & 1) ? xrA : xrB;
            const u64*   ro = (it & 1) ? rmB : rmA;
            u64*         rn = (it & 1) ? rmA : rmB;
            k_it<<<dim3(NA_ / 16, B_), dim3(256), 0, stream>>>(xp, xn, d, inv, dpk,
                                                               cm, ro, rn,
                                                               selA, selT, selV, it);
        }
    } else {
        float* xr = ws + OFF_SXR;
        u64* cand = (u64*)(ws + OFF_SCAND);
        s_init<<<dim3((B_ * T_ + 255) / 256), dim3(256), 0, stream>>>(x, xr, cand);
        for (int it = 0; it < NIT_; ++it) {
            s_scan<<<dim3(NA_, B_), dim3(256), 0, stream>>>(xr, d, inv, cand);
            s_apply<<<dim3(B_), dim3(256), 0, stream>>>(xr, d, inv, cand, selA, selT, selV, it);
        }
    }

    k_final<<<dim3(B_ * T_ / 256), dim3(256), 0, stream>>>(x, d, selA, selT, selV, inv, out);
}

// Round 13
// 1166.244 us; speedup vs baseline: 3.9606x; 1.1332x over previous
//
#include <hip/hip_runtime.h>
#include <cstdint>

#define B_    8
#define T_    16384
#define NA_   512
#define A_    512
#define NIT_  32
#define NCH_  256           // 64-sample chunks per row
#define EPSV  1e-8f

typedef unsigned long long u64;
typedef __attribute__((ext_vector_type(8))) short bf16x8;
typedef __attribute__((ext_vector_type(4))) float f32x4;

// ws float-offset layout (~10.6 MB total)
#define OFF_INV   0
#define OFF_SELA  512
#define OFF_SELT  768
#define OFF_SELV  1024
#define OFF_CM    1280        // u64[8*512*256] -> 2,097,152 floats
#define OFF_RMA   2098432     // u64[4096]
#define OFF_RMB   2106624     // u64[4096]
#define OFF_XRA   2114816     // f32[8*16384]
#define OFF_XRB   2245888     // f32[8*16384]
#define OFF_DPK   2376960     // u32[512*512]   d as (hi|lo<<16)
#define MAIN_NEED 2639104
// compact fallback layout
#define OFF_SXR   OFF_CM
#define OFF_SCAND (OFF_CM + 131072)
#define S_NEED    (OFF_SCAND + 16)

__device__ __forceinline__ unsigned int encf(float f) {
    unsigned int u = __float_as_uint(f);
    return (u & 0x80000000u) ? ~u : (u | 0x80000000u);
}
__device__ __forceinline__ float decf(unsigned int e) {
    unsigned int u = (e & 0x80000000u) ? (e & 0x7fffffffu) : ~e;
    return __uint_as_float(u);
}
__device__ __forceinline__ u64 umax64(u64 a, u64 b) { return a > b ? a : b; }
__device__ __forceinline__ u64 enc64(float v, unsigned int flat) {
    return (((u64)encf(v)) << 32) | (unsigned int)~flat;
}
__device__ __forceinline__ u64 shfl_xor_u64(u64 v, int mask) {
    unsigned int lo = (unsigned int)v, hi = (unsigned int)(v >> 32);
    lo = __shfl_xor(lo, mask, 64);
    hi = __shfl_xor(hi, mask, 64);
    return (((u64)hi) << 32) | lo;
}
__device__ __forceinline__ u64 shfl_down_u64(u64 v, int off) {
    unsigned int lo = (unsigned int)v, hi = (unsigned int)(v >> 32);
    lo = __shfl_down(lo, off, 64);
    hi = __shfl_down(hi, off, 64);
    return (((u64)hi) << 32) | lo;
}
// bf16 round-to-nearest-even from fp32
__device__ __forceinline__ unsigned short f2bf(float v) {
    unsigned int u = __float_as_uint(v);
    return (unsigned short)((u + 0x7fffu + ((u >> 16) & 1u)) >> 16);
}

// ---------------- inv[a] = 1/(||d_a||+eps) ----------------
__global__ __launch_bounds__(64) void k_inv(const float* __restrict__ d, float* __restrict__ inv) {
    const int a = blockIdx.x, lane = threadIdx.x;
    const float* row = d + a * A_;
    float s = 0.f;
    for (int i = lane; i < A_; i += 64) { float v = row[i]; s = fmaf(v, v, s); }
    #pragma unroll
    for (int o = 32; o > 0; o >>= 1) s += __shfl_down(s, o, 64);
    if (lane == 0) inv[a] = 1.0f / (sqrtf(s) + EPSV);
}

// ---------------- d -> packed (hi | lo<<16) ----------------
__global__ __launch_bounds__(256) void k_split_d(const float* __restrict__ d,
                                                 unsigned int* __restrict__ dpk) {
    int id = blockIdx.x * 256 + threadIdx.x;           // 262144
    float v = d[id];
    unsigned short hb = f2bf(v);
    unsigned short lb = f2bf(v - __uint_as_float((unsigned int)hb << 16));
    dpk[id] = (unsigned int)hb | ((unsigned int)lb << 16);
}

// ---------------- initial full conv: 128 atoms x 256 t per block, LDS B-sharing ----------------
// LDS copy stride 202 uint4 = 808 dwords == 8 (mod 32): conflict-free b128 reads.
// blocks with blockIdx.y==0 also persist x into xrA (replaces the memcpy node).
__global__ __launch_bounds__(512) void k_conv(const float* __restrict__ x,
                                              const unsigned int* __restrict__ dpk,
                                              const float* __restrict__ inv,
                                              u64* __restrict__ cm,
                                              float* __restrict__ xrA) {
    __shared__ float xf[776];
    __shared__ uint4 s_hh[4][202];
    __shared__ uint4 s_ll[4][202];
    const int tid = threadIdx.x;
    const int wave = tid >> 6, lane = tid & 63;
    const int cl = lane & 15, q = lane >> 4;
    const int wb = blockIdx.x * 256;
    const int gb = blockIdx.z;

    for (int i = tid; i < 776; i += 512) {
        int t = wb + i;
        float xv = (t < T_) ? x[gb * T_ + t] : 0.f;
        xf[i] = xv;
        if (blockIdx.y == 0 && i < 256) xrA[gb * T_ + wb + i] = xv;
    }
    __syncthreads();
    unsigned int* hw = (unsigned int*)s_hh;
    unsigned int* lw = (unsigned int*)s_ll;
    for (int i = tid; i < 772; i += 512) {
        #pragma unroll
        for (int s = 0; s < 4; ++s) {
            float xv = xf[i + s];
            unsigned short hb = f2bf(xv);
            unsigned short lb = f2bf(xv - __uint_as_float((unsigned int)hb << 16));
            hw[s * 808 + i] = (unsigned int)hb * 0x10001u;
            lw[s * 808 + i] = (unsigned int)lb * 0x10001u;
        }
    }
    __syncthreads();

    const int a_base = blockIdx.y * 128 + (wave & 1) * 64;
    const int t0l = (wave >> 1) * 64;
    const unsigned int* Ap[4];
    #pragma unroll
    for (int at = 0; at < 4; ++at)
        Ap[at] = dpk + ((a_base + 16 * at + cl) << 9) + 4 * q;
    const uint4* bhp = &s_hh[cl & 3][(t0l >> 2) + (cl >> 2) + q];
    const uint4* blp = &s_ll[cl & 3][(t0l >> 2) + (cl >> 2) + q];

    f32x4 acc[4][4];
    const f32x4 zero = {0.f, 0.f, 0.f, 0.f};
    #pragma unroll
    for (int at = 0; at < 4; ++at)
        #pragma unroll
        for (int tt = 0; tt < 4; ++tt) acc[at][tt] = zero;

    for (int j0 = 0; j0 < A_; j0 += 16) {
        union { uint4 u; bf16x8 f; } Af[4], bh[4], bl[4];
        #pragma unroll
        for (int at = 0; at < 4; ++at) Af[at].u = *(const uint4*)(Ap[at] + j0);
        #pragma unroll
        for (int tt = 0; tt < 4; ++tt) {
            bh[tt].u = bhp[4 * tt + (j0 >> 2)];
            bl[tt].u = blp[4 * tt + (j0 >> 2)];
        }
        #pragma unroll
        for (int tt = 0; tt < 4; ++tt)
            #pragma unroll
            for (int at = 0; at < 4; ++at)
                acc[at][tt] = __builtin_amdgcn_mfma_f32_16x16x32_bf16(Af[at].f, bh[tt].f, acc[at][tt], 0, 0, 0);
        #pragma unroll
        for (int tt = 0; tt < 4; ++tt)
            #pragma unroll
            for (int at = 0; at < 4; ++at)
                acc[at][tt] = __builtin_amdgcn_mfma_f32_16x16x32_bf16(Af[at].f, bl[tt].f, acc[at][tt], 0, 0, 0);
    }

    const int t0 = wb + t0l;
    const int ch = t0 >> 6;
    #pragma unroll
    for (int at = 0; at < 4; ++at) {
        #pragma unroll
        for (int r = 0; r < 4; ++r) {
            const int atom = a_base + 16 * at + 4 * q + r;
            const float iv = inv[atom];
            u64 m = 0ull;
            #pragma unroll
            for (int tt = 0; tt < 4; ++tt) {
                int t = t0 + 16 * tt + cl;
                m = umax64(m, enc64(acc[at][tt][r] * iv, (unsigned int)(atom * T_ + t)));
            }
            m = umax64(m, shfl_xor_u64(m, 1));
            m = umax64(m, shfl_xor_u64(m, 2));
            m = umax64(m, shfl_xor_u64(m, 4));
            m = umax64(m, shfl_xor_u64(m, 8));
            if (cl == 0)
                cm[((size_t)(gb * NA_ + atom) << 8) + ch] = m;
        }
    }
}

// ---------------- rm from cm (4 rows per block, wave per row) ----------------
__global__ __launch_bounds__(256) void k_tables(const u64* __restrict__ cm, u64* __restrict__ rm) {
    const int row = blockIdx.x * 4 + (threadIdx.x >> 6);
    const int lane = threadIdx.x & 63;
    const u64* p = cm + ((size_t)row << 8);
    u64 m = 0ull;
    #pragma unroll
    for (int k = 0; k < 4; ++k) m = umax64(m, p[lane + 64 * k]);
    #pragma unroll
    for (int o = 32; o > 0; o >>= 1) m = umax64(m, shfl_down_u64(m, o));
    if (lane == 0) rm[row] = m;
}

// ---------------- fully fused per-iteration kernel (512 threads, 8 waves) ----------------
// grid (32 atom-groups of 16, 8 batches). Each block OWNS its 16 cm/rm rows
// (phase D writes them, phase E rescans them) -> no cross-block deps inside a
// launch; next iteration's argmax dependency rides the launch boundary.
// 8 waves = 2 waves/SIMD: halves staging time, D chunks/wave 5 -> 3.
// LDS copy stride 410 uint4 = 1640 dwords == 8 (mod 32): conflict-free.
__global__ __launch_bounds__(512) void k_it(const float* __restrict__ xrPrev,
                                            float* __restrict__ xrNext,
                                            const float* __restrict__ d,
                                            const float* __restrict__ inv,
                                            const unsigned int* __restrict__ dpk,
                                            u64* __restrict__ cm,
                                            const u64* __restrict__ rmPrev,
                                            u64* __restrict__ rmNext,
                                            int* __restrict__ selA,
                                            int* __restrict__ selT,
                                            float* __restrict__ selV,
                                            int it) {
    __shared__ u64 red8[8];
    __shared__ float xf[1604];
    __shared__ uint4 s_hh[4][410];
    __shared__ uint4 s_ll[4][410];
    const int ag = blockIdx.x, b = blockIdx.y, tid = threadIdx.x;
    const int wave = tid >> 6, lane = tid & 63;
    const int cl = lane & 15, q = lane >> 4;
    const int a0 = ag * 16;

    // ---- phase A: argmax from rmPrev (shfl-reduce, 1 barrier) ----
    const u64* rp = rmPrev + b * NA_;
    u64 am = rp[tid];
    #pragma unroll
    for (int o = 32; o > 0; o >>= 1) am = umax64(am, shfl_xor_u64(am, o));
    if (lane == 0) red8[wave] = am;
    __syncthreads();
    u64 win = red8[0];
    #pragma unroll
    for (int w2 = 1; w2 < 8; ++w2) win = umax64(win, red8[w2]);
    const unsigned int enc = (unsigned int)(win >> 32);
    const unsigned int flat = ~(unsigned int)win;
    // defensive clamps: garbage rm (poison / replay anomaly) must not fault
    const int asel = (int)((flat >> 14) & (NA_ - 1));
    const int tsel = (int)(flat & (T_ - 1));
    const float v = decf(enc);
    if (ag == 0 && tid == 0) {
        selA[it * B_ + b] = asel;
        selT[it * B_ + b] = tsel;
        selV[it * B_ + b] = v;
    }
    const int L = min(A_, (T_ - 1) - tsel);   // reference truncation quirk
    const float vv = v * inv[asel];

    // ---- phase B: xr ping-pong slice [ag*512, +512) ----
    {
        int t = ag * 512 + tid;
        float xv = xrPrev[b * T_ + t];
        int o = t - tsel;
        if (L > 0 && o >= 0 && o < L) xv = fmaf(-vv, d[asel * A_ + o], xv);
        xrNext[b * T_ + t] = xv;
    }

    if (L > 0) {
        const int tbeg = max(0, tsel - (A_ - 1));
        const int tend = tsel + L;               // <= 16383
        const int ab = tbeg & ~63;
        const int ae = (tend + 63) & ~63;        // <= T_
        const int W = ae - ab;                   // <= 1088 (window <=1023 + rounding)
        const int nch = W >> 6;                  // <= 17
        const int NS = W + 512;                  // <= 1600

        // ---- phase C: patched fp32 window, then 4 shift-copies of bf16 pairs ----
        __syncthreads();
        for (int i = tid; i < NS + 3; i += 512) {
            int t = ab + i;
            float xv = (t < T_) ? xrPrev[b * T_ + t] : 0.f;
            int o = t - tsel;
            if (o >= 0 && o < L) xv = fmaf(-vv, d[asel * A_ + o], xv);
            xf[i] = xv;
        }
        __syncthreads();
        unsigned int* hw = (unsigned int*)s_hh;
        unsigned int* lw = (unsigned int*)s_ll;
        for (int i = tid; i < NS; i += 512) {
            #pragma unroll
            for (int s = 0; s < 4; ++s) {
                float xv = xf[i + s];
                unsigned short hb = f2bf(xv);
                unsigned short lb = f2bf(xv - __uint_as_float((unsigned int)hb << 16));
                hw[s * 1640 + i] = (unsigned int)hb * 0x10001u;
                lw[s * 1640 + i] = (unsigned int)lb * 0x10001u;
            }
        }
        __syncthreads();

        // ---- phase D: chunks c = wave, wave+8, ... (<=3 per wave) ----
        const unsigned int* Ap = dpk + ((a0 + cl) << 9) + 4 * q;
        float ivv[4];
        #pragma unroll
        for (int r = 0; r < 4; ++r) ivv[r] = inv[a0 + 4 * q + r];
        const uint4* bhp = &s_hh[cl & 3][(cl >> 2) + q];
        const uint4* blp = &s_ll[cl & 3][(cl >> 2) + q];

        for (int c = wave; c < nch; c += 8) {
            f32x4 acc[4];
            const f32x4 zero = {0.f, 0.f, 0.f, 0.f};
            #pragma unroll
            for (int tt = 0; tt < 4; ++tt) acc[tt] = zero;
            for (int j0 = 0; j0 < A_; j0 += 16) {
                union { uint4 u; bf16x8 f; } Af, bh[4], bl[4];
                Af.u = *(const uint4*)(Ap + j0);
                #pragma unroll
                for (int tt = 0; tt < 4; ++tt) {
                    int i4 = 16 * c + 4 * tt + (j0 >> 2);
                    bh[tt].u = bhp[i4];
                    bl[tt].u = blp[i4];
                }
                #pragma unroll
                for (int tt = 0; tt < 4; ++tt)
                    acc[tt] = __builtin_amdgcn_mfma_f32_16x16x32_bf16(Af.f, bh[tt].f, acc[tt], 0, 0, 0);
                #pragma unroll
                for (int tt = 0; tt < 4; ++tt)
                    acc[tt] = __builtin_amdgcn_mfma_f32_16x16x32_bf16(Af.f, bl[tt].f, acc[tt], 0, 0, 0);
            }
            #pragma unroll
            for (int r = 0; r < 4; ++r) {
                const int atom = a0 + 4 * q + r;
                u64 mm = 0ull;
                #pragma unroll
                for (int tt = 0; tt < 4; ++tt) {
                    int t = ab + 64 * c + 16 * tt + cl;
                    mm = umax64(mm, enc64(acc[tt][r] * ivv[r], (unsigned int)(atom * T_ + t)));
                }
                mm = umax64(mm, shfl_xor_u64(mm, 1));
                mm = umax64(mm, shfl_xor_u64(mm, 2));
                mm = umax64(mm, shfl_xor_u64(mm, 4));
                mm = umax64(mm, shfl_xor_u64(mm, 8));
                if (cl == 0)
                    cm[((size_t)(b * NA_ + atom) << 8) + (ab >> 6) + c] = mm;
            }
        }
        __syncthreads();   // own-row cm writes visible block-wide
    }

    // ---- phase E: rm for this block's 16 rows, wave per 2 rows, lane-coalesced ----
    #pragma unroll
    for (int rr = 0; rr < 2; ++rr) {
        const int row = a0 + wave * 2 + rr;
        const u64* p = cm + ((size_t)(b * NA_ + row) << 8);
        u64 m = umax64(umax64(p[lane], p[lane + 64]),
                       umax64(p[lane + 128], p[lane + 192]));
        #pragma unroll
        for (int o = 32; o > 0; o >>= 1) m = umax64(m, shfl_down_u64(m, o));
        if (lane == 0) rmNext[b * NA_ + row] = m;
    }
}

// ---------------- slow fallback (tiny ws): residual-space recompute ----------------
__global__ void s_init(const float* __restrict__ x, float* __restrict__ xr,
                       u64* __restrict__ cand) {
    int i = blockIdx.x * 256 + threadIdx.x;
    if (i < B_ * T_) xr[i] = x[i];
    if (i < B_) cand[i] = 0ull;
}
__global__ __launch_bounds__(256) void s_scan(const float* __restrict__ xr,
                                              const float* __restrict__ d,
                                              const float* __restrict__ inv,
                                              u64* __restrict__ cand) {
    __shared__ float dLs[A_];
    __shared__ u64 redU[256];
    const int aB = blockIdx.x, b = blockIdx.y, tid = threadIdx.x;
    const float iv = inv[aB];
    for (int i = tid; i < A_; i += 256) dLs[i] = d[aB * A_ + i] * iv;
    __syncthreads();
    const float* xb = xr + b * T_;
    u64 best = 0ull;
    for (int t = tid; t < T_; t += 256) {
        float acc = 0.f;
        int lim = min(A_, T_ - t);
        for (int i = 0; i < lim; ++i) acc = fmaf(dLs[i], xb[t + i], acc);
        best = umax64(best, enc64(acc, (unsigned int)(aB * T_ + t)));
    }
    redU[tid] = best;
    __syncthreads();
    for (int s = 128; s > 0; s >>= 1) {
        if (tid < s) redU[tid] = umax64(redU[tid], redU[tid + s]);
        __syncthreads();
    }
    if (tid == 0) atomicMax(&cand[b], redU[0]);
}
__global__ void s_apply(float* __restrict__ xr, const float* __restrict__ d,
                        const float* __restrict__ inv, u64* __restrict__ cand,
                        int* selA, int* selT, float* selV, int it) {
    const int b = blockIdx.x, tid = threadIdx.x;
    u64 win = cand[b];
    unsigned int enc = (unsigned int)(win >> 32);
    unsigned int flat = ~(unsigned int)win;
    int a = (int)((flat >> 14) & (NA_ - 1)), t = (int)(flat & (T_ - 1));
    float v = decf(enc);
    if (tid == 0) { selA[it * B_ + b] = a; selT[it * B_ + b] = t; selV[it * B_ + b] = v; }
    float vvl = v * inv[a];
    int L = min(A_, (T_ - 1) - t);
    for (int o = tid; o < L; o += 256) xr[b * T_ + t + o] -= vvl * d[a * A_ + o];
    if (tid == 0) cand[b] = 0ull;
}

// ---------------- reconstruct (residual, recon) from selections ----------------
__global__ __launch_bounds__(256) void k_final(const float* __restrict__ x,
                                               const float* __restrict__ d,
                                               const int* __restrict__ selA,
                                               const int* __restrict__ selT,
                                               const float* __restrict__ selV,
                                               const float* __restrict__ inv,
                                               float* __restrict__ out) {
    const int gid = blockIdx.x * 256 + threadIdx.x;
    const int b = gid >> 14;
    const int t = gid & (T_ - 1);
    float r = x[gid];
    float rec = 0.f;
    for (int k = 0; k < NIT_; ++k) {           // sequential: reference fp order
        int a  = selA[k * B_ + b] & (NA_ - 1);
        int ts = selT[k * B_ + b] & (T_ - 1);
        float vvl = selV[k * B_ + b] * inv[a];
        int o = t - ts;
        int L = min(A_, (T_ - 1) - ts);
        if (o >= 0 && o < L) {
            float c = vvl * d[a * A_ + o];
            r -= c;
            rec += c;
        }
    }
    out[gid] = r;
    out[B_ * T_ + gid] = rec;
}

extern "C" void kernel_launch(void* const* d_in, const int* in_sizes, int n_in,
                              void* d_out, int out_size, void* d_ws, size_t ws_size,
                              hipStream_t stream) {
    const float* x = (const float*)d_in[0];
    const float* d = (const float*)d_in[1];
    float* out = (float*)d_out;
    float* ws = (float*)d_ws;
    const size_t wsf = ws_size / sizeof(float);

    float* inv  = ws + OFF_INV;
    int*   selA = (int*)(ws + OFF_SELA);
    int*   selT = (int*)(ws + OFF_SELT);
    float* selV = ws + OFF_SELV;

    if (wsf < (size_t)S_NEED) return;   // hopeless

    k_inv<<<dim3(NA_), dim3(64), 0, stream>>>(d, inv);

    if (wsf >= (size_t)MAIN_NEED) {
        u64* cm  = (u64*)(ws + OFF_CM);
        u64* rmA = (u64*)(ws + OFF_RMA);
        u64* rmB = (u64*)(ws + OFF_RMB);
        float* xrA = ws + OFF_XRA;
        float* xrB = ws + OFF_XRB;
        unsigned int* dpk = (unsigned int*)(ws + OFF_DPK);

        k_split_d<<<dim3(NA_ * A_ / 256), dim3(256), 0, stream>>>(d, dpk);
        k_conv<<<dim3(T_ / 256, NA_ / 128, B_), dim3(512), 0, stream>>>(x, dpk, inv, cm, xrA);
        k_tables<<<dim3(B_ * NA_ / 4), dim3(256), 0, stream>>>(cm, rmA);

        for (int it = 0; it < NIT_; ++it) {
            const float* xp = (it & 1) ? xrB : xrA;
            float*       xn = (it & 1) ? xrA : xrB;
            const u64*   ro = (it & 1) ? rmB : rmA;
            u64*         rn = (it & 1) ? rmA : rmB;
            k_it<<<dim3(NA_ / 16, B_), dim3(512), 0, stream>>>(xp, xn, d, inv, dpk,
                                                               cm, ro, rn,
                                                               selA, selT, selV, it);
        }
    } else {
        float* xr = ws + OFF_SXR;
        u64* cand = (u64*)(ws + OFF_SCAND);
        s_init<<<dim3((B_ * T_ + 255) / 256), dim3(256), 0, stream>>>(x, xr, cand);
        for (int it = 0; it < NIT_; ++it) {
            s_scan<<<dim3(NA_, B_), dim3(256), 0, stream>>>(xr, d, inv, cand);
            s_apply<<<dim3(B_), dim3(256), 0, stream>>>(xr, d, inv, cand, selA, selT, selV, it);
        }
    }

    k_final<<<dim3(B_ * T_ / 256), dim3(256), 0, stream>>>(x, d, selA, selT, selV, inv, out);
}